// Round 1
// baseline (309.497 us; speedup 1.0000x reference)
//
#include <hip/hip_runtime.h>
#include <hip/hip_bf16.h>

typedef unsigned int u32;
typedef unsigned short u16;

#define DEVINL __device__ __forceinline__

// Problem constants (fixed instance): B=8, C=64, D=128, H=128, W=128
constexpr int XS = 132;                 // u16 stride for LDS rows (264 B, 8B-aligned rows)
constexpr int LDS_X = 128 * XS * 2;     // 33792 B per scan buffer
constexpr int LDS_MAIN = LDS_X * 2 + 8192;  // 75776 B (X + HL + Meff chunk)

DEVINL float bf2f(u16 u) { union { u32 i; float f; } v; v.i = ((u32)u) << 16; return v.f; }
DEVINL float bf2f_lo(u32 u) { union { u32 i; float f; } v; v.i = u << 16; return v.f; }
DEVINL float bf2f_hi(u32 u) { union { u32 i; float f; } v; v.i = u & 0xffff0000u; return v.f; }
DEVINL u16 f2bf(float f) {
  union { float f; u32 i; } v; v.f = f;
  u32 b = v.i;
  b += 0x7fffu + ((b >> 16) & 1u);   // RNE
  return (u16)(b >> 16);
}

// ---------------- P0: precompute A=tanh(A_param), MeffT, beff ----------------
// MeffT layout: [dir][d][c] bf16, dir in {lr,rl,tb,bt}, d<128, c<64
__global__ __launch_bounds__(256) void k_pre(
    const float* __restrict__ Wf, const float* __restrict__ Wo,
    const float* __restrict__ bf_, const float* __restrict__ bo,
    const float* __restrict__ A_param,
    float* __restrict__ A_t, float* __restrict__ beff, u16* __restrict__ MeffT) {
  const int wg = blockIdx.x, t = threadIdx.x;
  if (wg < 128) {
    const int idx = wg * 256 + t;          // 0..32767
    const int cout = idx >> 9;             // 0..63
    const int k = idx & 511;               // 0..511
    float s = 0.f;
    for (int d = 0; d < 128; ++d) s = fmaf(Wo[cout * 128 + d], Wf[d * 512 + k], s);
    const int dir = k >> 7, dm = k & 127;
    MeffT[(dir * 128 + dm) * 64 + cout] = f2bf(s);
  } else {
    if (t < 128) A_t[t] = tanhf(A_param[t]);
    if (t < 64) {
      float s = bo[t];
      for (int d = 0; d < 128; ++d) s = fmaf(Wo[t * 128 + d], bf_[d], s);
      beff[t] = s;
    }
  }
}

extern __shared__ char smem[];

// ---------------- P1: x = Wi@F_mod + bi, scans lr/rl, combine ----------------
// One WG per (b,h). Writes x (bf16) for the vertical pass and the raw
// horizontal contribution S_h (f32) into d_out.
__global__ __launch_bounds__(256, 2) void k_horiz(
    const float* __restrict__ F_in, const float* __restrict__ prior,
    const float* __restrict__ Wi, const float* __restrict__ bi,
    const float* __restrict__ Bp, const float* __restrict__ alpha_p,
    const float* __restrict__ A_t, const u16* __restrict__ MeffT,
    u16* __restrict__ x_out, float* __restrict__ out_partial) {
  u16* Xu  = (u16*)smem;                    // x, then h_rl (in-place)
  u16* HLu = (u16*)(smem + LDS_X);          // copy of x, then h_lr (in-place)
  float* WiT = (float*)(smem + LDS_X);      // phase-1 union with HLu
  u16* Mc  = (u16*)(smem + 2 * LDS_X);      // Meff chunk [2][32][64]
  float* OutS = (float*)smem;               // phase-4 union with Xu

  const int t = threadIdx.x;
  const int bid = blockIdx.x, b = bid >> 7, h = bid & 127;

  // WiT[c][d] = Wi[d][c] (fp32, uniform broadcast reads later)
  for (int i = t; i < 8192; i += 256) {
    const int d = i >> 6, c = i & 63;
    WiT[c * 128 + d] = Wi[i];
  }
  __syncthreads();

  // ---- x compute: thread = (w, d-half), acc in regs ----
  {
    const int w = t & 127, dh = t >> 7;
    const float alpha = alpha_p[0];
    const float pv = prior[(b * 128 + h) * 128 + w];
    float xacc[64];
#pragma unroll
    for (int k = 0; k < 64; ++k) xacc[k] = bi[dh * 64 + k];
    const float* Fb = F_in + (b * 64 * 128 + h) * 128 + w;
    for (int c = 0; c < 64; ++c) {
      const float f = fmaf(alpha, pv, Fb[c * 16384]);
      const float* wrow = WiT + c * 128 + dh * 64;
#pragma unroll
      for (int q = 0; q < 16; ++q) {
        const float4 wv = *(const float4*)(wrow + q * 4);
        xacc[q * 4 + 0] = fmaf(wv.x, f, xacc[q * 4 + 0]);
        xacc[q * 4 + 1] = fmaf(wv.y, f, xacc[q * 4 + 1]);
        xacc[q * 4 + 2] = fmaf(wv.z, f, xacc[q * 4 + 2]);
        xacc[q * 4 + 3] = fmaf(wv.w, f, xacc[q * 4 + 3]);
      }
    }
    u16* xg = x_out + (b * 128 + dh * 64) * 16384 + h * 128 + w;
#pragma unroll 8
    for (int k = 0; k < 64; ++k) {
      const u16 u = f2bf(xacc[k]);
      xg[k * 16384] = u;                      // coalesced across lanes per k
      Xu[(dh * 64 + k) * XS + w] = u;
    }
  }
  __syncthreads();

  // ---- copy X -> HL so both scan directions are independent ----
  {
    const u32* src = (const u32*)Xu;
    u32* dst = (u32*)HLu;
    for (int i = t; i < 128 * XS / 2; i += 256) dst[i] = src[i];
  }
  __syncthreads();

  // ---- scans: thread = (d, dir); in-place overwrite is safe per-position ----
  {
    const int d = t & 127, dir = t >> 7;
    const float A = A_t[d], Bv = Bp[d];
    float hv = 0.f;
    if (dir == 0) {                 // left->right into HL
      u16* row = HLu + d * XS;
      for (int i = 0; i < 128; ++i) { hv = fmaf(A, hv, Bv * bf2f(row[i])); row[i] = f2bf(hv); }
    } else {                        // right->left into X
      u16* row = Xu + d * XS;
      for (int i = 127; i >= 0; --i) { hv = fmaf(A, hv, Bv * bf2f(row[i])); row[i] = f2bf(hv); }
    }
  }
  __syncthreads();

  // ---- combine: S_h[c][w] = sum_d ML[c,d]*h_lr[d,w] + MR[c,d]*h_rl[d,w] ----
  {
    const int wq = t & 31, cg = t >> 5, w0 = wq * 4, c0 = cg * 8;
    float acc[8][4];
#pragma unroll
    for (int i = 0; i < 8; ++i)
#pragma unroll
      for (int j = 0; j < 4; ++j) acc[i][j] = 0.f;

    for (int ch = 0; ch < 4; ++ch) {
      for (int i = t; i < 4096; i += 256) {
        const int m = i >> 11, dd = (i >> 6) & 31, c = i & 63;
        Mc[i] = MeffT[(m * 128 + ch * 32 + dd) * 64 + c];
      }
      __syncthreads();
      for (int dd = 0; dd < 32; ++dd) {
        const int d = ch * 32 + dd;
        const uint2 hlu = *(const uint2*)(HLu + d * XS + w0);
        const uint2 hru = *(const uint2*)(Xu + d * XS + w0);
        const float hl[4] = { bf2f_lo(hlu.x), bf2f_hi(hlu.x), bf2f_lo(hlu.y), bf2f_hi(hlu.y) };
        const float hr[4] = { bf2f_lo(hru.x), bf2f_hi(hru.x), bf2f_lo(hru.y), bf2f_hi(hru.y) };
        const uint4 mlu = *(const uint4*)(Mc + dd * 64 + c0);
        const uint4 mru = *(const uint4*)(Mc + 2048 + dd * 64 + c0);
        const float ml[8] = { bf2f_lo(mlu.x), bf2f_hi(mlu.x), bf2f_lo(mlu.y), bf2f_hi(mlu.y),
                              bf2f_lo(mlu.z), bf2f_hi(mlu.z), bf2f_lo(mlu.w), bf2f_hi(mlu.w) };
        const float mr[8] = { bf2f_lo(mru.x), bf2f_hi(mru.x), bf2f_lo(mru.y), bf2f_hi(mru.y),
                              bf2f_lo(mru.z), bf2f_hi(mru.z), bf2f_lo(mru.w), bf2f_hi(mru.w) };
#pragma unroll
        for (int cc = 0; cc < 8; ++cc)
#pragma unroll
          for (int ww = 0; ww < 4; ++ww)
            acc[cc][ww] = fmaf(ml[cc], hl[ww], fmaf(mr[cc], hr[ww], acc[cc][ww]));
      }
      __syncthreads();
    }
    // stage to LDS (Xu region is dead now) for coalesced global write
#pragma unroll
    for (int cc = 0; cc < 8; ++cc)
#pragma unroll
      for (int ww = 0; ww < 4; ++ww)
        OutS[(c0 + cc) * XS + w0 + ww] = acc[cc][ww];
  }
  __syncthreads();
  {
    float* og = out_partial + (b * 64 * 128 + h) * 128;
    for (int j = 0; j < 32; ++j) {
      const int idx = j * 256 + t, c = idx >> 7, w = idx & 127;
      og[c * 16384 + w] = OutS[c * XS + w];
    }
  }
}

// ---------------- T: x[b,d,h,w] -> xt[b,d,w,h] ----------------
__global__ __launch_bounds__(256) void k_trans(const u16* __restrict__ x, u16* __restrict__ xt) {
  u16* Xu = (u16*)smem;     // [128][132]
  u32* Xw = (u32*)smem;
  const int t = threadIdx.x;
  const int base = blockIdx.x * 16384;   // (b,d) plane
  for (int i = t; i < 2048; i += 256) {
    const int r = i >> 4, j = i & 15;
    const uint4 v = *(const uint4*)(x + base + r * 128 + j * 8);
    u32* dst = Xw + r * 66 + j * 4;
    dst[0] = v.x; dst[1] = v.y; dst[2] = v.z; dst[3] = v.w;
  }
  __syncthreads();
  for (int i = t; i < 2048; i += 256) {
    const int wr = i >> 4, j8 = (i & 15) * 8;
    u16 e[8];
#pragma unroll
    for (int q = 0; q < 8; ++q) e[q] = Xu[(j8 + q) * XS + wr];
    uint4 o;
    o.x = (u32)e[0] | ((u32)e[1] << 16);
    o.y = (u32)e[2] | ((u32)e[3] << 16);
    o.z = (u32)e[4] | ((u32)e[5] << 16);
    o.w = (u32)e[6] | ((u32)e[7] << 16);
    *(uint4*)(xt + base + wr * 128 + j8) = o;
  }
}

// ---------------- P2: vertical scans tb/bt + combine -> accT[b,c,w,h] bf16 ----
__global__ __launch_bounds__(256, 2) void k_vert(
    const u16* __restrict__ xt, const float* __restrict__ Bp,
    const float* __restrict__ A_t, const u16* __restrict__ MeffT,
    u16* __restrict__ accT) {
  u16* Xu  = (u16*)smem;
  u16* HLu = (u16*)(smem + LDS_X);
  u16* Mc  = (u16*)(smem + 2 * LDS_X);
  float* OutS = (float*)smem;
  u32* Xw = (u32*)smem;

  const int t = threadIdx.x;
  const int bid = blockIdx.x, b = bid >> 7, w = bid & 127;

  // load xt rows (b,d,w,:) -> Xu[d][:]
  for (int i = t; i < 2048; i += 256) {
    const int d = i >> 4, j = i & 15;
    const uint4 v = *(const uint4*)(xt + (b * 128 + d) * 16384 + w * 128 + j * 8);
    u32* dst = Xw + d * 66 + j * 4;
    dst[0] = v.x; dst[1] = v.y; dst[2] = v.z; dst[3] = v.w;
  }
  __syncthreads();
  {
    const u32* src = (const u32*)Xu;
    u32* dst = (u32*)HLu;
    for (int i = t; i < 128 * XS / 2; i += 256) dst[i] = src[i];
  }
  __syncthreads();
  {
    const int d = t & 127, dir = t >> 7;
    const float A = A_t[d], Bv = Bp[d];
    float hv = 0.f;
    if (dir == 0) {                 // top->bottom
      u16* row = HLu + d * XS;
      for (int i = 0; i < 128; ++i) { hv = fmaf(A, hv, Bv * bf2f(row[i])); row[i] = f2bf(hv); }
    } else {                        // bottom->top
      u16* row = Xu + d * XS;
      for (int i = 127; i >= 0; --i) { hv = fmaf(A, hv, Bv * bf2f(row[i])); row[i] = f2bf(hv); }
    }
  }
  __syncthreads();
  {
    const int hq = t & 31, cg = t >> 5, h0 = hq * 4, c0 = cg * 8;
    float acc[8][4];
#pragma unroll
    for (int i = 0; i < 8; ++i)
#pragma unroll
      for (int j = 0; j < 4; ++j) acc[i][j] = 0.f;

    for (int ch = 0; ch < 4; ++ch) {
      for (int i = t; i < 4096; i += 256) {
        const int m = i >> 11, dd = (i >> 6) & 31, c = i & 63;
        Mc[i] = MeffT[((m + 2) * 128 + ch * 32 + dd) * 64 + c];
      }
      __syncthreads();
      for (int dd = 0; dd < 32; ++dd) {
        const int d = ch * 32 + dd;
        const uint2 hlu = *(const uint2*)(HLu + d * XS + h0);
        const uint2 hru = *(const uint2*)(Xu + d * XS + h0);
        const float hl[4] = { bf2f_lo(hlu.x), bf2f_hi(hlu.x), bf2f_lo(hlu.y), bf2f_hi(hlu.y) };
        const float hr[4] = { bf2f_lo(hru.x), bf2f_hi(hru.x), bf2f_lo(hru.y), bf2f_hi(hru.y) };
        const uint4 mlu = *(const uint4*)(Mc + dd * 64 + c0);
        const uint4 mru = *(const uint4*)(Mc + 2048 + dd * 64 + c0);
        const float ml[8] = { bf2f_lo(mlu.x), bf2f_hi(mlu.x), bf2f_lo(mlu.y), bf2f_hi(mlu.y),
                              bf2f_lo(mlu.z), bf2f_hi(mlu.z), bf2f_lo(mlu.w), bf2f_hi(mlu.w) };
        const float mr[8] = { bf2f_lo(mru.x), bf2f_hi(mru.x), bf2f_lo(mru.y), bf2f_hi(mru.y),
                              bf2f_lo(mru.z), bf2f_hi(mru.z), bf2f_lo(mru.w), bf2f_hi(mru.w) };
#pragma unroll
        for (int cc = 0; cc < 8; ++cc)
#pragma unroll
          for (int ww = 0; ww < 4; ++ww)
            acc[cc][ww] = fmaf(ml[cc], hl[ww], fmaf(mr[cc], hr[ww], acc[cc][ww]));
      }
      __syncthreads();
    }
#pragma unroll
    for (int cc = 0; cc < 8; ++cc)
#pragma unroll
      for (int ww = 0; ww < 4; ++ww)
        OutS[(c0 + cc) * XS + h0 + ww] = acc[cc][ww];
  }
  __syncthreads();
  {
    u16* og = accT + (b * 64) * 16384 + w * 128;
    for (int j = 0; j < 32; ++j) {
      const int idx = j * 256 + t, c = idx >> 7, hh = idx & 127;
      og[c * 16384 + hh] = f2bf(OutS[c * XS + hh]);
    }
  }
}

// ---------------- F: out = F_mod + gamma*(S_h + S_v^T + beff) ----------------
__global__ __launch_bounds__(256) void k_final(
    const float* __restrict__ F_in, const float* __restrict__ prior,
    const float* __restrict__ alpha_p, const float* __restrict__ gamma_p,
    const float* __restrict__ beff, const u16* __restrict__ accT,
    float* __restrict__ out) {
  u16* Xu = (u16*)smem;
  u32* Xw = (u32*)smem;
  const int t = threadIdx.x;
  const int bid = blockIdx.x, b = bid >> 6, c = bid & 63;
  const int base = bid * 16384;   // (b,c) plane

  for (int i = t; i < 2048; i += 256) {
    const int r = i >> 4, j = i & 15;   // r = w row of accT plane
    const uint4 v = *(const uint4*)(accT + base + r * 128 + j * 8);
    u32* dst = Xw + r * 66 + j * 4;
    dst[0] = v.x; dst[1] = v.y; dst[2] = v.z; dst[3] = v.w;
  }
  __syncthreads();
  const float alpha = alpha_p[0], gamma = gamma_p[0];
  const float be = beff[c];
  for (int i = t; i < 2048; i += 256) {
    const int hh = i >> 4, w8 = (i & 15) * 8;
    float sv[8];
#pragma unroll
    for (int q = 0; q < 8; ++q) sv[q] = bf2f(Xu[(w8 + q) * XS + hh]);
    const int off = base + hh * 128 + w8;
    const float* Fp = F_in + off;
    float* Op = out + off;
    const float* Pp = prior + (b * 128 + hh) * 128 + w8;
#pragma unroll
    for (int q = 0; q < 8; ++q) {
      Op[q] = Fp[q] + alpha * Pp[q] + gamma * (Op[q] + be + sv[q]);
    }
  }
}

extern "C" void kernel_launch(void* const* d_in, const int* in_sizes, int n_in,
                              void* d_out, int out_size, void* d_ws, size_t ws_size,
                              hipStream_t stream) {
  const float* F_in   = (const float*)d_in[0];
  const float* prior  = (const float*)d_in[1];
  const float* Wi     = (const float*)d_in[2];
  const float* bi     = (const float*)d_in[3];
  const float* A_par  = (const float*)d_in[4];
  const float* B_par  = (const float*)d_in[5];
  const float* alpha  = (const float*)d_in[6];
  const float* gamma  = (const float*)d_in[7];
  const float* Wf     = (const float*)d_in[8];
  const float* bf_    = (const float*)d_in[9];
  const float* Wo     = (const float*)d_in[10];
  const float* bo     = (const float*)d_in[11];
  float* out = (float*)d_out;

  char* ws = (char*)d_ws;
  float* A_t   = (float*)ws;                       // 512 B
  float* beff  = (float*)(ws + 512);               // 256 B
  u16*   MeffT = (u16*)(ws + 1024);                // 65536 B
  u16*   x_ws  = (u16*)(ws + 66560);               // 33.5 MB
  u16*   xt_ws = (u16*)(ws + 66560 + 33554432);    // 33.5 MB
  u16*   accT  = (u16*)(ws + 66560 + 67108864);    // 16.8 MB

  hipFuncSetAttribute((const void*)k_horiz, hipFuncAttributeMaxDynamicSharedMemorySize, LDS_MAIN);
  hipFuncSetAttribute((const void*)k_vert,  hipFuncAttributeMaxDynamicSharedMemorySize, LDS_MAIN);

  k_pre  <<<129, 256, 0, stream>>>(Wf, Wo, bf_, bo, A_par, A_t, beff, MeffT);
  k_horiz<<<1024, 256, LDS_MAIN, stream>>>(F_in, prior, Wi, bi, B_par, alpha, A_t, MeffT, x_ws, out);
  k_trans<<<1024, 256, LDS_X, stream>>>(x_ws, xt_ws);
  k_vert <<<1024, 256, LDS_MAIN, stream>>>(xt_ws, B_par, A_t, MeffT, accT);
  k_final<<<512, 256, LDS_X, stream>>>(F_in, prior, alpha, gamma, beff, accT, out);
}

// Round 2
// 290.175 us; speedup vs baseline: 1.0666x; 1.0666x over previous
//
#include <hip/hip_runtime.h>
#include <hip/hip_bf16.h>

typedef unsigned int u32;
typedef unsigned short u16;
typedef float f32x2 __attribute__((ext_vector_type(2)));
typedef float f32x4 __attribute__((ext_vector_type(4)));

#define DEVINL __device__ __forceinline__

// Problem constants (fixed instance): B=8, C=64, D=128, H=128, W=128
constexpr int XS = 132;                 // u16 stride for LDS rows (264 B, 8B-aligned rows)
constexpr int LDS_X = 128 * XS * 2;     // 33792 B per scan buffer
constexpr int LDS_MAIN = LDS_X * 2 + 8192;  // 75776 B (X + HL + Meff chunk)

DEVINL float bf2f(u16 u) { union { u32 i; float f; } v; v.i = ((u32)u) << 16; return v.f; }
DEVINL float bf2f_lo(u32 u) { union { u32 i; float f; } v; v.i = u << 16; return v.f; }
DEVINL float bf2f_hi(u32 u) { union { u32 i; float f; } v; v.i = u & 0xffff0000u; return v.f; }
DEVINL u16 f2bf(float f) {
  union { float f; u32 i; } v; v.f = f;
  u32 b = v.i;
  b += 0x7fffu + ((b >> 16) & 1u);   // RNE
  return (u16)(b >> 16);
}

// ---------------- P0: precompute A=tanh(A_param), MeffT, beff ----------------
// MeffT layout: [dir][d][c] bf16, dir in {lr,rl,tb,bt}, d<128, c<64
__global__ __launch_bounds__(256) void k_pre(
    const float* __restrict__ Wf, const float* __restrict__ Wo,
    const float* __restrict__ bf_, const float* __restrict__ bo,
    const float* __restrict__ A_param,
    float* __restrict__ A_t, float* __restrict__ beff, u16* __restrict__ MeffT) {
  const int wg = blockIdx.x, t = threadIdx.x;
  if (wg < 128) {
    const int idx = wg * 256 + t;          // 0..32767
    const int cout = idx >> 9;             // 0..63
    const int k = idx & 511;               // 0..511
    float s = 0.f;
    for (int d = 0; d < 128; ++d) s = fmaf(Wo[cout * 128 + d], Wf[d * 512 + k], s);
    const int dir = k >> 7, dm = k & 127;
    MeffT[(dir * 128 + dm) * 64 + cout] = f2bf(s);
  } else {
    if (t < 128) A_t[t] = tanhf(A_param[t]);
    if (t < 64) {
      float s = bo[t];
      for (int d = 0; d < 128; ++d) s = fmaf(Wo[t * 128 + d], bf_[d], s);
      beff[t] = s;
    }
  }
}

extern __shared__ char smem[];

// ---------------- P1: x = Wi@F_mod + bi, scans lr/rl, combine ----------------
__global__ __launch_bounds__(256, 2) void k_horiz(
    const float* __restrict__ F_in, const float* __restrict__ prior,
    const float* __restrict__ Wi, const float* __restrict__ bi,
    const float* __restrict__ Bp, const float* __restrict__ alpha_p,
    const float* __restrict__ A_t, const u16* __restrict__ MeffT,
    u16* __restrict__ x_out, float* __restrict__ out_partial) {
  u16* Xu  = (u16*)smem;                    // x, then h_rl (in-place)
  u16* HLu = (u16*)(smem + LDS_X);          // copy of x, then h_lr (in-place)
  float* WiT = (float*)(smem + LDS_X);      // phase-1 union with HLu
  u16* Mc  = (u16*)(smem + 2 * LDS_X);      // Meff chunk [2][32][64]
  float* OutS = (float*)smem;               // phase-4 union with Xu

  const int t = threadIdx.x;
  const int bid = blockIdx.x, b = bid >> 7, h = bid & 127;

  // WiT[c][d] = Wi[d][c] (fp32, uniform broadcast reads later)
  for (int i = t; i < 8192; i += 256) {
    const int d = i >> 6, c = i & 63;
    WiT[c * 128 + d] = Wi[i];
  }
  __syncthreads();

  // ---- x compute: thread = (w, d-half); acc fully in regs (static idx) ----
  {
    const int w = t & 127, dh = t >> 7;
    const float alpha = alpha_p[0];
    const float pv = prior[(b * 128 + h) * 128 + w];
    f32x2 xacc[32];
#pragma unroll
    for (int q = 0; q < 32; ++q) xacc[q] = *(const f32x2*)(bi + dh * 64 + q * 2);
    const float* Fb = F_in + (b * 64 * 128 + h) * 128 + w;
    for (int cc = 0; cc < 64; cc += 8) {
      float fv[8];
#pragma unroll
      for (int j = 0; j < 8; ++j) fv[j] = Fb[(cc + j) * 16384];   // 8 loads in flight
#pragma unroll
      for (int j = 0; j < 8; ++j) {
        const float f = fmaf(alpha, pv, fv[j]);
        const f32x2 fb = { f, f };
        const float* wrow = WiT + (cc + j) * 128 + dh * 64;
#pragma unroll
        for (int q = 0; q < 16; ++q) {
          const f32x4 wv = *(const f32x4*)(wrow + q * 4);
          f32x2 w0; w0.x = wv.x; w0.y = wv.y;
          f32x2 w1; w1.x = wv.z; w1.y = wv.w;
          xacc[q * 2 + 0] += w0 * fb;    // v_pk_fma_f32
          xacc[q * 2 + 1] += w1 * fb;
        }
      }
    }
    u16* xg = x_out + (b * 128 + dh * 64) * 16384 + h * 128 + w;
#pragma unroll
    for (int q = 0; q < 32; ++q) {
      const u16 u0 = f2bf(xacc[q].x);
      const u16 u1 = f2bf(xacc[q].y);
      xg[(q * 2 + 0) * 16384] = u0;
      xg[(q * 2 + 1) * 16384] = u1;
      Xu[(dh * 64 + q * 2 + 0) * XS + w] = u0;
      Xu[(dh * 64 + q * 2 + 1) * XS + w] = u1;
    }
  }
  __syncthreads();

  // ---- copy X -> HL so both scan directions are independent ----
  {
    const u32* src = (const u32*)Xu;
    u32* dst = (u32*)HLu;
    for (int i = t; i < 128 * XS / 2; i += 256) dst[i] = src[i];
  }
  __syncthreads();

  // ---- scans: thread = (d, dir) ----
  {
    const int d = t & 127, dir = t >> 7;
    const float A = A_t[d], Bv = Bp[d];
    float hv = 0.f;
    if (dir == 0) {                 // left->right into HL
      u16* row = HLu + d * XS;
      for (int i = 0; i < 128; ++i) { hv = fmaf(A, hv, Bv * bf2f(row[i])); row[i] = f2bf(hv); }
    } else {                        // right->left into X
      u16* row = Xu + d * XS;
      for (int i = 127; i >= 0; --i) { hv = fmaf(A, hv, Bv * bf2f(row[i])); row[i] = f2bf(hv); }
    }
  }
  __syncthreads();

  // ---- combine: S_h[c][w] = sum_d ML[c,d]*h_lr[d,w] + MR[c,d]*h_rl[d,w] ----
  {
    const int wq = t & 31, cg = t >> 5, w0 = wq * 4, c0 = cg * 8;
    f32x2 acc2[8][2];
#pragma unroll
    for (int i = 0; i < 8; ++i) { acc2[i][0] = 0.f; acc2[i][1] = 0.f; }

    for (int ch = 0; ch < 4; ++ch) {
      for (int i = t; i < 4096; i += 256) {
        const int m = i >> 11, dd = (i >> 6) & 31, c = i & 63;
        Mc[i] = MeffT[(m * 128 + ch * 32 + dd) * 64 + c];
      }
      __syncthreads();
      for (int dd = 0; dd < 32; ++dd) {
        const int d = ch * 32 + dd;
        const uint2 hlu = *(const uint2*)(HLu + d * XS + w0);
        const uint2 hru = *(const uint2*)(Xu + d * XS + w0);
        f32x2 hl2[2], hr2[2];
        hl2[0].x = bf2f_lo(hlu.x); hl2[0].y = bf2f_hi(hlu.x);
        hl2[1].x = bf2f_lo(hlu.y); hl2[1].y = bf2f_hi(hlu.y);
        hr2[0].x = bf2f_lo(hru.x); hr2[0].y = bf2f_hi(hru.x);
        hr2[1].x = bf2f_lo(hru.y); hr2[1].y = bf2f_hi(hru.y);
        const uint4 mlu = *(const uint4*)(Mc + dd * 64 + c0);
        const uint4 mru = *(const uint4*)(Mc + 2048 + dd * 64 + c0);
        const float ml[8] = { bf2f_lo(mlu.x), bf2f_hi(mlu.x), bf2f_lo(mlu.y), bf2f_hi(mlu.y),
                              bf2f_lo(mlu.z), bf2f_hi(mlu.z), bf2f_lo(mlu.w), bf2f_hi(mlu.w) };
        const float mr[8] = { bf2f_lo(mru.x), bf2f_hi(mru.x), bf2f_lo(mru.y), bf2f_hi(mru.y),
                              bf2f_lo(mru.z), bf2f_hi(mru.z), bf2f_lo(mru.w), bf2f_hi(mru.w) };
#pragma unroll
        for (int cc = 0; cc < 8; ++cc) {
          const f32x2 mlv = { ml[cc], ml[cc] };
          const f32x2 mrv = { mr[cc], mr[cc] };
#pragma unroll
          for (int p = 0; p < 2; ++p) {
            acc2[cc][p] += mlv * hl2[p];   // v_pk_fma_f32
            acc2[cc][p] += mrv * hr2[p];
          }
        }
      }
      __syncthreads();
    }
#pragma unroll
    for (int cc = 0; cc < 8; ++cc) {
      OutS[(c0 + cc) * XS + w0 + 0] = acc2[cc][0].x;
      OutS[(c0 + cc) * XS + w0 + 1] = acc2[cc][0].y;
      OutS[(c0 + cc) * XS + w0 + 2] = acc2[cc][1].x;
      OutS[(c0 + cc) * XS + w0 + 3] = acc2[cc][1].y;
    }
  }
  __syncthreads();
  {
    float* og = out_partial + (b * 64 * 128 + h) * 128;
    for (int j = 0; j < 32; ++j) {
      const int idx = j * 256 + t, c = idx >> 7, w = idx & 127;
      og[c * 16384 + w] = OutS[c * XS + w];
    }
  }
}

// ---------------- T: x[b,d,h,w] -> xt[b,d,w,h] ----------------
__global__ __launch_bounds__(256) void k_trans(const u16* __restrict__ x, u16* __restrict__ xt) {
  u16* Xu = (u16*)smem;     // [128][132]
  u32* Xw = (u32*)smem;
  const int t = threadIdx.x;
  const int base = blockIdx.x * 16384;   // (b,d) plane
  for (int i = t; i < 2048; i += 256) {
    const int r = i >> 4, j = i & 15;
    const uint4 v = *(const uint4*)(x + base + r * 128 + j * 8);
    u32* dst = Xw + r * 66 + j * 4;
    dst[0] = v.x; dst[1] = v.y; dst[2] = v.z; dst[3] = v.w;
  }
  __syncthreads();
  for (int i = t; i < 2048; i += 256) {
    const int wr = i >> 4, j8 = (i & 15) * 8;
    u16 e[8];
#pragma unroll
    for (int q = 0; q < 8; ++q) e[q] = Xu[(j8 + q) * XS + wr];
    uint4 o;
    o.x = (u32)e[0] | ((u32)e[1] << 16);
    o.y = (u32)e[2] | ((u32)e[3] << 16);
    o.z = (u32)e[4] | ((u32)e[5] << 16);
    o.w = (u32)e[6] | ((u32)e[7] << 16);
    *(uint4*)(xt + base + wr * 128 + j8) = o;
  }
}

// ---------------- P2: vertical scans tb/bt + combine -> accT[b,c,w,h] bf16 ----
__global__ __launch_bounds__(256, 2) void k_vert(
    const u16* __restrict__ xt, const float* __restrict__ Bp,
    const float* __restrict__ A_t, const u16* __restrict__ MeffT,
    u16* __restrict__ accT) {
  u16* Xu  = (u16*)smem;
  u16* HLu = (u16*)(smem + LDS_X);
  u16* Mc  = (u16*)(smem + 2 * LDS_X);
  float* OutS = (float*)smem;
  u32* Xw = (u32*)smem;

  const int t = threadIdx.x;
  const int bid = blockIdx.x, b = bid >> 7, w = bid & 127;

  // load xt rows (b,d,w,:) -> Xu[d][:]
  for (int i = t; i < 2048; i += 256) {
    const int d = i >> 4, j = i & 15;
    const uint4 v = *(const uint4*)(xt + (b * 128 + d) * 16384 + w * 128 + j * 8);
    u32* dst = Xw + d * 66 + j * 4;
    dst[0] = v.x; dst[1] = v.y; dst[2] = v.z; dst[3] = v.w;
  }
  __syncthreads();
  {
    const u32* src = (const u32*)Xu;
    u32* dst = (u32*)HLu;
    for (int i = t; i < 128 * XS / 2; i += 256) dst[i] = src[i];
  }
  __syncthreads();
  {
    const int d = t & 127, dir = t >> 7;
    const float A = A_t[d], Bv = Bp[d];
    float hv = 0.f;
    if (dir == 0) {                 // top->bottom
      u16* row = HLu + d * XS;
      for (int i = 0; i < 128; ++i) { hv = fmaf(A, hv, Bv * bf2f(row[i])); row[i] = f2bf(hv); }
    } else {                        // bottom->top
      u16* row = Xu + d * XS;
      for (int i = 127; i >= 0; --i) { hv = fmaf(A, hv, Bv * bf2f(row[i])); row[i] = f2bf(hv); }
    }
  }
  __syncthreads();
  {
    const int hq = t & 31, cg = t >> 5, h0 = hq * 4, c0 = cg * 8;
    f32x2 acc2[8][2];
#pragma unroll
    for (int i = 0; i < 8; ++i) { acc2[i][0] = 0.f; acc2[i][1] = 0.f; }

    for (int ch = 0; ch < 4; ++ch) {
      for (int i = t; i < 4096; i += 256) {
        const int m = i >> 11, dd = (i >> 6) & 31, c = i & 63;
        Mc[i] = MeffT[((m + 2) * 128 + ch * 32 + dd) * 64 + c];
      }
      __syncthreads();
      for (int dd = 0; dd < 32; ++dd) {
        const int d = ch * 32 + dd;
        const uint2 hlu = *(const uint2*)(HLu + d * XS + h0);
        const uint2 hru = *(const uint2*)(Xu + d * XS + h0);
        f32x2 hl2[2], hr2[2];
        hl2[0].x = bf2f_lo(hlu.x); hl2[0].y = bf2f_hi(hlu.x);
        hl2[1].x = bf2f_lo(hlu.y); hl2[1].y = bf2f_hi(hlu.y);
        hr2[0].x = bf2f_lo(hru.x); hr2[0].y = bf2f_hi(hru.x);
        hr2[1].x = bf2f_lo(hru.y); hr2[1].y = bf2f_hi(hru.y);
        const uint4 mlu = *(const uint4*)(Mc + dd * 64 + c0);
        const uint4 mru = *(const uint4*)(Mc + 2048 + dd * 64 + c0);
        const float ml[8] = { bf2f_lo(mlu.x), bf2f_hi(mlu.x), bf2f_lo(mlu.y), bf2f_hi(mlu.y),
                              bf2f_lo(mlu.z), bf2f_hi(mlu.z), bf2f_lo(mlu.w), bf2f_hi(mlu.w) };
        const float mr[8] = { bf2f_lo(mru.x), bf2f_hi(mru.x), bf2f_lo(mru.y), bf2f_hi(mru.y),
                              bf2f_lo(mru.z), bf2f_hi(mru.z), bf2f_lo(mru.w), bf2f_hi(mru.w) };
#pragma unroll
        for (int cc = 0; cc < 8; ++cc) {
          const f32x2 mlv = { ml[cc], ml[cc] };
          const f32x2 mrv = { mr[cc], mr[cc] };
#pragma unroll
          for (int p = 0; p < 2; ++p) {
            acc2[cc][p] += mlv * hl2[p];
            acc2[cc][p] += mrv * hr2[p];
          }
        }
      }
      __syncthreads();
    }
#pragma unroll
    for (int cc = 0; cc < 8; ++cc) {
      OutS[(c0 + cc) * XS + h0 + 0] = acc2[cc][0].x;
      OutS[(c0 + cc) * XS + h0 + 1] = acc2[cc][0].y;
      OutS[(c0 + cc) * XS + h0 + 2] = acc2[cc][1].x;
      OutS[(c0 + cc) * XS + h0 + 3] = acc2[cc][1].y;
    }
  }
  __syncthreads();
  {
    u16* og = accT + (b * 64) * 16384 + w * 128;
    for (int j = 0; j < 32; ++j) {
      const int idx = j * 256 + t, c = idx >> 7, hh = idx & 127;
      og[c * 16384 + hh] = f2bf(OutS[c * XS + hh]);
    }
  }
}

// ---------------- F: out = F_mod + gamma*(S_h + S_v^T + beff) ----------------
__global__ __launch_bounds__(256) void k_final(
    const float* __restrict__ F_in, const float* __restrict__ prior,
    const float* __restrict__ alpha_p, const float* __restrict__ gamma_p,
    const float* __restrict__ beff, const u16* __restrict__ accT,
    float* __restrict__ out) {
  u16* Xu = (u16*)smem;
  u32* Xw = (u32*)smem;
  const int t = threadIdx.x;
  const int bid = blockIdx.x, b = bid >> 6, c = bid & 63;
  const int base = bid * 16384;   // (b,c) plane

  for (int i = t; i < 2048; i += 256) {
    const int r = i >> 4, j = i & 15;   // r = w row of accT plane
    const uint4 v = *(const uint4*)(accT + base + r * 128 + j * 8);
    u32* dst = Xw + r * 66 + j * 4;
    dst[0] = v.x; dst[1] = v.y; dst[2] = v.z; dst[3] = v.w;
  }
  __syncthreads();
  const float alpha = alpha_p[0], gamma = gamma_p[0];
  const float be = beff[c];
  for (int i = t; i < 2048; i += 256) {
    const int hh = i >> 4, w8 = (i & 15) * 8;
    float sv[8];
#pragma unroll
    for (int q = 0; q < 8; ++q) sv[q] = bf2f(Xu[(w8 + q) * XS + hh]);
    const int off = base + hh * 128 + w8;
    const float* Fp = F_in + off;
    float* Op = out + off;
    const float* Pp = prior + (b * 128 + hh) * 128 + w8;
#pragma unroll
    for (int q = 0; q < 8; ++q) {
      Op[q] = Fp[q] + alpha * Pp[q] + gamma * (Op[q] + be + sv[q]);
    }
  }
}

extern "C" void kernel_launch(void* const* d_in, const int* in_sizes, int n_in,
                              void* d_out, int out_size, void* d_ws, size_t ws_size,
                              hipStream_t stream) {
  const float* F_in   = (const float*)d_in[0];
  const float* prior  = (const float*)d_in[1];
  const float* Wi     = (const float*)d_in[2];
  const float* bi     = (const float*)d_in[3];
  const float* A_par  = (const float*)d_in[4];
  const float* B_par  = (const float*)d_in[5];
  const float* alpha  = (const float*)d_in[6];
  const float* gamma  = (const float*)d_in[7];
  const float* Wf     = (const float*)d_in[8];
  const float* bf_    = (const float*)d_in[9];
  const float* Wo     = (const float*)d_in[10];
  const float* bo     = (const float*)d_in[11];
  float* out = (float*)d_out;

  char* ws = (char*)d_ws;
  float* A_t   = (float*)ws;                       // 512 B
  float* beff  = (float*)(ws + 512);               // 256 B
  u16*   MeffT = (u16*)(ws + 1024);                // 65536 B
  u16*   x_ws  = (u16*)(ws + 66560);               // 33.5 MB
  u16*   xt_ws = (u16*)(ws + 66560 + 33554432);    // 33.5 MB
  u16*   accT  = (u16*)(ws + 66560 + 67108864);    // 16.8 MB

  hipFuncSetAttribute((const void*)k_horiz, hipFuncAttributeMaxDynamicSharedMemorySize, LDS_MAIN);
  hipFuncSetAttribute((const void*)k_vert,  hipFuncAttributeMaxDynamicSharedMemorySize, LDS_MAIN);

  k_pre  <<<129, 256, 0, stream>>>(Wf, Wo, bf_, bo, A_par, A_t, beff, MeffT);
  k_horiz<<<1024, 256, LDS_MAIN, stream>>>(F_in, prior, Wi, bi, B_par, alpha, A_t, MeffT, x_ws, out);
  k_trans<<<1024, 256, LDS_X, stream>>>(x_ws, xt_ws);
  k_vert <<<1024, 256, LDS_MAIN, stream>>>(xt_ws, B_par, A_t, MeffT, accT);
  k_final<<<512, 256, LDS_X, stream>>>(F_in, prior, alpha, gamma, beff, accT, out);
}

// Round 3
// 128.589 us; speedup vs baseline: 2.4069x; 2.2566x over previous
//
#include <hip/hip_runtime.h>
#include <hip/hip_bf16.h>

typedef unsigned int u32;
typedef unsigned short u16;
typedef float f32x2 __attribute__((ext_vector_type(2)));
typedef float f32x4 __attribute__((ext_vector_type(4)));
using bf16x8 = __attribute__((ext_vector_type(8))) short;   // MFMA A/B frag (4 VGPRs)
using f32x4v = __attribute__((ext_vector_type(4))) float;   // MFMA C/D frag

#define DEVINL __device__ __forceinline__

// Problem constants: B=8, C=64, D=128, H=128, W=128
constexpr int XTS = 136;                     // u16 stride for [pos][d] LDS rows (272 B, 16B-mult)
constexpr int XT_BYTES = 128 * XTS * 2;      // 34816
constexpr int MC_STRIDE = 40;                // u16 stride for Mc rows (80 B, 16B-mult)
constexpr int LDS_MAIN = 2 * XT_BYTES + 64 * MC_STRIDE * 2;  // 74752
constexpr int XS = 132;                      // legacy stride for k_final
constexpr int LDS_X = 128 * XS * 2;          // 33792

DEVINL float bf2f(u16 u) { union { u32 i; float f; } v; v.i = ((u32)u) << 16; return v.f; }
DEVINL u16 f2bf(float f) {
  union { float f; u32 i; } v; v.f = f;
  u32 b = v.i;
  b += 0x7fffu + ((b >> 16) & 1u);   // RNE
  return (u16)(b >> 16);
}
DEVINL u32 pack2(float a, float b) { return (u32)f2bf(a) | ((u32)f2bf(b) << 16); }

// ---------------- P0: A=tanh(A_param), Mrow[dir][c][d] bf16, beff ----------------
__global__ __launch_bounds__(256) void k_pre(
    const float* __restrict__ Wf, const float* __restrict__ Wo,
    const float* __restrict__ bf_, const float* __restrict__ bo,
    const float* __restrict__ A_param,
    float* __restrict__ A_t, float* __restrict__ beff, u16* __restrict__ Mrow) {
  const int wg = blockIdx.x, t = threadIdx.x;
  if (wg < 128) {
    const int idx = wg * 256 + t;          // 0..32767
    const int cout = idx >> 9;             // 0..63
    const int k = idx & 511;               // 0..511 = dir*128 + d
    float s = 0.f;
    for (int d = 0; d < 128; ++d) s = fmaf(Wo[cout * 128 + d], Wf[d * 512 + k], s);
    const int dir = k >> 7, dm = k & 127;
    Mrow[(dir * 64 + cout) * 128 + dm] = f2bf(s);
  } else {
    if (t < 128) A_t[t] = tanhf(A_param[t]);
    if (t < 64) {
      float s = bo[t];
      for (int d = 0; d < 128; ++d) s = fmaf(Wo[t * 128 + d], bf_[d], s);
      beff[t] = s;
    }
  }
}

extern __shared__ char smem[];

// Shared combine: S[64c x 128pos] = sum over 2 dirs of M[dir] @ h[dir], MFMA.
// Hbuf0/Hbuf1 hold h as [pos][k] bf16, stride XTS. Result into OutS (f32, stride 134).
DEVINL void combine_mfma(const u16* Hbuf0, const u16* Hbuf1, u16* Mc,
                         const u16* __restrict__ Mrow, int dir_base,
                         int t, float* OutS) {
  const int lane = t & 63, wv = t >> 6;
  f32x4v acc[4][2];
#pragma unroll
  for (int i = 0; i < 4; ++i)
#pragma unroll
    for (int j = 0; j < 2; ++j) acc[i][j] = (f32x4v)0.f;

  const int l15 = lane & 15;
  const int kgrp = (lane >> 4) * 16;     // byte offset of this lane's 8-k group

#pragma unroll
  for (int dir = 0; dir < 2; ++dir) {
    const u16* Hsrc = dir ? Hbuf1 : Hbuf0;
    const u16* Msrc = Mrow + (size_t)(dir_base + dir) * 8192;
#pragma unroll
    for (int ks = 0; ks < 4; ++ks) {
      __syncthreads();   // previous frag reads done / scans done
      {
        const int c = t >> 2, q = t & 3;   // 256 threads = 64 rows x 4 chunks
        const uint4 v = *(const uint4*)(Msrc + c * 128 + ks * 32 + q * 8);
        *(uint4*)((char*)Mc + c * (MC_STRIDE * 2) + q * 16) = v;
      }
      __syncthreads();
      bf16x8 afr[4], bfr[2];
#pragma unroll
      for (int ct = 0; ct < 4; ++ct)
        afr[ct] = *(const bf16x8*)((const char*)Mc + (ct * 16 + l15) * (MC_STRIDE * 2) + kgrp);
#pragma unroll
      for (int pt = 0; pt < 2; ++pt)
        bfr[pt] = *(const bf16x8*)((const char*)Hsrc + (wv * 32 + pt * 16 + l15) * (XTS * 2) + ks * 64 + kgrp);
#pragma unroll
      for (int ct = 0; ct < 4; ++ct)
#pragma unroll
        for (int pt = 0; pt < 2; ++pt)
          acc[ct][pt] = __builtin_amdgcn_mfma_f32_16x16x32_bf16(afr[ct], bfr[pt], acc[ct][pt], 0, 0, 0);
    }
  }
  __syncthreads();   // all Hsrc reads done before OutS overwrites Xt region
#pragma unroll
  for (int ct = 0; ct < 4; ++ct)
#pragma unroll
    for (int pt = 0; pt < 2; ++pt)
#pragma unroll
      for (int r = 0; r < 4; ++r)
        OutS[(ct * 16 + (lane >> 4) * 4 + r) * 134 + wv * 32 + pt * 16 + l15] = acc[ct][pt][r];
  __syncthreads();
}

// ---------------- P1: x = Wi@F_mod + bi, scans lr/rl, MFMA combine ----------------
__global__ __launch_bounds__(256, 2) void k_horiz(
    const float* __restrict__ F_in, const float* __restrict__ prior,
    const float* __restrict__ Wi, const float* __restrict__ bi,
    const float* __restrict__ Bp, const float* __restrict__ alpha_p,
    const float* __restrict__ A_t, const u16* __restrict__ Mrow,
    u16* __restrict__ x_out, float* __restrict__ out_partial) {
  u16* Xt = (u16*)smem;                     // [128 pos][XTS] : x, then h_rl (in place)
  u16* Hl = (u16*)(smem + XT_BYTES);        // copy of x, then h_lr (in place)
  u16* Mc = (u16*)(smem + 2 * XT_BYTES);    // [64][MC_STRIDE]
  float* WiT = (float*)(smem + XT_BYTES);   // phase-1 union with Hl
  float* OutS = (float*)smem;               // epilogue union with Xt

  const int t = threadIdx.x;
  const int bid = blockIdx.x, b = bid >> 7, h = bid & 127;

  for (int i = t; i < 8192; i += 256) {
    const int d = i >> 6, c = i & 63;
    WiT[c * 128 + d] = Wi[i];
  }
  __syncthreads();

  // ---- x-compute: thread = (w, dh); acc fully in regs ----
  {
    const int w = t & 127, dh = t >> 7;
    const float alpha = alpha_p[0];
    const float pv = prior[(b * 128 + h) * 128 + w];
    f32x2 xacc[32];
#pragma unroll
    for (int q = 0; q < 32; ++q) xacc[q] = *(const f32x2*)(bi + dh * 64 + q * 2);
    const float* Fb = F_in + (size_t)b * 1048576 + h * 128 + w;
    for (int cc = 0; cc < 64; cc += 8) {
      float fv[8];
#pragma unroll
      for (int j = 0; j < 8; ++j) fv[j] = Fb[(cc + j) * 16384];
#pragma unroll
      for (int j = 0; j < 8; ++j) {
        const float f = fmaf(alpha, pv, fv[j]);
        const f32x2 fb = { f, f };
        const float* wrow = WiT + (cc + j) * 128 + dh * 64;
#pragma unroll
        for (int q = 0; q < 16; ++q) {
          const f32x4 wv = *(const f32x4*)(wrow + q * 4);
          f32x2 w0; w0.x = wv.x; w0.y = wv.y;
          f32x2 w1; w1.x = wv.z; w1.y = wv.w;
          xacc[q * 2 + 0] += w0 * fb;
          xacc[q * 2 + 1] += w1 * fb;
        }
      }
    }
    // pack 64 bf16 -> Xt row w (contiguous 128B at d-offset dh*64)
    char* row = (char*)Xt + w * (XTS * 2) + dh * 128;
#pragma unroll
    for (int q = 0; q < 8; ++q) {
      uint4 v;
      v.x = pack2(xacc[q * 4 + 0].x, xacc[q * 4 + 0].y);
      v.y = pack2(xacc[q * 4 + 1].x, xacc[q * 4 + 1].y);
      v.z = pack2(xacc[q * 4 + 2].x, xacc[q * 4 + 2].y);
      v.w = pack2(xacc[q * 4 + 3].x, xacc[q * 4 + 3].y);
      *(uint4*)(row + q * 16) = v;
    }
  }
  __syncthreads();

  // ---- coalesced x_out write + Xt -> Hl copy ----
  {
    u16* xg = x_out + (size_t)(b * 128 + h) * 16384;   // [w][d] plane
    for (int i = t; i < 2048; i += 256) {
      const int r = i >> 4, q = i & 15;
      const uint4 v = *(const uint4*)((const char*)Xt + r * (XTS * 2) + q * 16);
      *(uint4*)(xg + r * 128 + q * 8) = v;
    }
    for (int i = t; i < XT_BYTES / 16; i += 256)
      *(uint4*)((char*)Hl + i * 16) = *(const uint4*)((const char*)Xt + i * 16);
  }
  __syncthreads();

  // ---- scans in place: lr in Hl, rl in Xt ----
  {
    const int d = t & 127, dir = t >> 7;
    const float A = A_t[d], Bv = Bp[d];
    float hv = 0.f;
    if (dir == 0) {
      for (int i = 0; i < 128; ++i) {
        u16* p = Hl + i * XTS + d;
        hv = fmaf(A, hv, Bv * bf2f(*p)); *p = f2bf(hv);
      }
    } else {
      for (int i = 127; i >= 0; --i) {
        u16* p = Xt + i * XTS + d;
        hv = fmaf(A, hv, Bv * bf2f(*p)); *p = f2bf(hv);
      }
    }
  }

  combine_mfma(Hl, Xt, Mc, Mrow, 0, t, OutS);

  // ---- OutS -> out_partial[b][c][h][w] (raw, pre-gamma) ----
  float* og = out_partial + ((size_t)b * 64 * 128 + h) * 128;
  for (int i = t; i < 8192; i += 256) {
    const int c = i >> 7, ww = i & 127;
    og[c * 16384 + ww] = OutS[c * 134 + ww];
  }
}

// ---------------- P2: vertical scans tb/bt + MFMA combine -> accT[b,c,w,h] ----------------
__global__ __launch_bounds__(256, 2) void k_vert(
    const u16* __restrict__ x_ws, const float* __restrict__ Bp,
    const float* __restrict__ A_t, const u16* __restrict__ Mrow,
    u16* __restrict__ accT) {
  u16* Xv = (u16*)smem;                     // [128 h][XTS] : x, then h_bt
  u16* Hv = (u16*)(smem + XT_BYTES);        // copy, then h_tb
  u16* Mc = (u16*)(smem + 2 * XT_BYTES);
  float* OutS = (float*)smem;

  const int t = threadIdx.x;
  const int bid = blockIdx.x, b = bid >> 7, w = bid & 127;

  // load x[b][h][w][:] rows (256B granules) -> Xv[h][d]
  for (int i = t; i < 2048; i += 256) {
    const int hh = i >> 4, q = i & 15;
    const uint4 v = *(const uint4*)(x_ws + ((size_t)(b * 128 + hh) * 128 + w) * 128 + q * 8);
    *(uint4*)((char*)Xv + hh * (XTS * 2) + q * 16) = v;
  }
  __syncthreads();
  for (int i = t; i < XT_BYTES / 16; i += 256)
    *(uint4*)((char*)Hv + i * 16) = *(const uint4*)((const char*)Xv + i * 16);
  __syncthreads();

  // scans: tb in Hv (ascending h), bt in Xv (descending)
  {
    const int d = t & 127, dir = t >> 7;
    const float A = A_t[d], Bv = Bp[d];
    float hv = 0.f;
    if (dir == 0) {
      for (int i = 0; i < 128; ++i) {
        u16* p = Hv + i * XTS + d;
        hv = fmaf(A, hv, Bv * bf2f(*p)); *p = f2bf(hv);
      }
    } else {
      for (int i = 127; i >= 0; --i) {
        u16* p = Xv + i * XTS + d;
        hv = fmaf(A, hv, Bv * bf2f(*p)); *p = f2bf(hv);
      }
    }
  }

  combine_mfma(Hv, Xv, Mc, Mrow, 2, t, OutS);

  // ---- OutS (S_v[c][h] at fixed w) -> accT[b][c][w][h] bf16, packed u32 ----
  for (int i = t; i < 4096; i += 256) {
    const int c = i >> 6, h2 = (i & 63) * 2;
    const u32 pk = pack2(OutS[c * 134 + h2], OutS[c * 134 + h2 + 1]);
    *(u32*)(accT + ((size_t)(b * 64 + c) * 128 + w) * 128 + h2) = pk;
  }
}

// ---------------- F: out = F_mod + gamma*(S_h + S_v^T + beff) ----------------
__global__ __launch_bounds__(256) void k_final(
    const float* __restrict__ F_in, const float* __restrict__ prior,
    const float* __restrict__ alpha_p, const float* __restrict__ gamma_p,
    const float* __restrict__ beff, const u16* __restrict__ accT,
    float* __restrict__ out) {
  u16* Xu = (u16*)smem;
  u32* Xw = (u32*)smem;
  const int t = threadIdx.x;
  const int bid = blockIdx.x, b = bid >> 6, c = bid & 63;
  const size_t base = (size_t)bid * 16384;   // (b,c) plane

  for (int i = t; i < 2048; i += 256) {
    const int r = i >> 4, j = i & 15;   // r = w row of accT plane
    const uint4 v = *(const uint4*)(accT + base + r * 128 + j * 8);
    u32* dst = Xw + r * 66 + j * 4;
    dst[0] = v.x; dst[1] = v.y; dst[2] = v.z; dst[3] = v.w;
  }
  __syncthreads();
  const float alpha = alpha_p[0], gamma = gamma_p[0];
  const float be = beff[c];
  for (int i = t; i < 2048; i += 256) {
    const int hh = i >> 4, w8 = (i & 15) * 8;
    float sv[8];
#pragma unroll
    for (int q = 0; q < 8; ++q) sv[q] = bf2f(Xu[(w8 + q) * XS + hh]);
    const size_t off = base + hh * 128 + w8;
    const float* Fp = F_in + off;
    float* Op = out + off;
    const float* Pp = prior + (b * 128 + hh) * 128 + w8;
#pragma unroll
    for (int q = 0; q < 8; ++q) {
      Op[q] = Fp[q] + alpha * Pp[q] + gamma * (Op[q] + be + sv[q]);
    }
  }
}

extern "C" void kernel_launch(void* const* d_in, const int* in_sizes, int n_in,
                              void* d_out, int out_size, void* d_ws, size_t ws_size,
                              hipStream_t stream) {
  const float* F_in   = (const float*)d_in[0];
  const float* prior  = (const float*)d_in[1];
  const float* Wi     = (const float*)d_in[2];
  const float* bi     = (const float*)d_in[3];
  const float* A_par  = (const float*)d_in[4];
  const float* B_par  = (const float*)d_in[5];
  const float* alpha  = (const float*)d_in[6];
  const float* gamma  = (const float*)d_in[7];
  const float* Wf     = (const float*)d_in[8];
  const float* bf_    = (const float*)d_in[9];
  const float* Wo     = (const float*)d_in[10];
  const float* bo     = (const float*)d_in[11];
  float* out = (float*)d_out;

  char* ws = (char*)d_ws;
  float* A_t   = (float*)ws;                       // 512 B
  float* beff  = (float*)(ws + 512);               // 256 B
  u16*   Mrow  = (u16*)(ws + 1024);                // 64 KB: [4][64][128] bf16
  u16*   x_ws  = (u16*)(ws + 66560);               // 33.5 MB: x[b][h][w][d] bf16
  u16*   accT  = (u16*)(ws + 66560 + 33554432);    // 16.8 MB: [b][c][w][h] bf16

  hipFuncSetAttribute((const void*)k_horiz, hipFuncAttributeMaxDynamicSharedMemorySize, LDS_MAIN);
  hipFuncSetAttribute((const void*)k_vert,  hipFuncAttributeMaxDynamicSharedMemorySize, LDS_MAIN);

  k_pre  <<<129, 256, 0, stream>>>(Wf, Wo, bf_, bo, A_par, A_t, beff, Mrow);
  k_horiz<<<1024, 256, LDS_MAIN, stream>>>(F_in, prior, Wi, bi, B_par, alpha, A_t, Mrow, x_ws, out);
  k_vert <<<1024, 256, LDS_MAIN, stream>>>(x_ws, B_par, A_t, Mrow, accT);
  k_final<<<512, 256, LDS_X, stream>>>(F_in, prior, alpha, gamma, beff, accT, out);
}

// Round 4
// 108.575 us; speedup vs baseline: 2.8505x; 1.1843x over previous
//
#include <hip/hip_runtime.h>
#include <hip/hip_bf16.h>

typedef unsigned int u32;
typedef unsigned short u16;
typedef float f32x2 __attribute__((ext_vector_type(2)));
typedef float f32x4 __attribute__((ext_vector_type(4)));
using bf16x8 = __attribute__((ext_vector_type(8))) short;   // MFMA A/B frag (4 VGPRs)
using f32x4v = __attribute__((ext_vector_type(4))) float;   // MFMA C/D frag

#define DEVINL __device__ __forceinline__

// Problem constants: B=8, C=64, D=128, H=128, W=128
constexpr int XTS = 136;                     // u16 stride for [pos][d] LDS rows (272 B = 17*16)
constexpr int XT_BYTES = 128 * XTS * 2;      // 34816
constexpr int LDS_MAIN = 2 * XT_BYTES;       // 69632
constexpr int XS = 132;                      // stride for k_final
constexpr int LDS_X = 128 * XS * 2;          // 33792

DEVINL float bf2f(u16 u) { union { u32 i; float f; } v; v.i = ((u32)u) << 16; return v.f; }
DEVINL u16 f2bf(float f) {
  union { float f; u32 i; } v; v.f = f;
  u32 b = v.i;
  b += 0x7fffu + ((b >> 16) & 1u);   // RNE
  return (u16)(b >> 16);
}
DEVINL u32 pack2(float a, float b) { return (u32)f2bf(a) | ((u32)f2bf(b) << 16); }

// ---------------- P0: A=tanh(A_param), Mrow[dir][c][d] bf16, beff ----------------
__global__ __launch_bounds__(256) void k_pre(
    const float* __restrict__ Wf, const float* __restrict__ Wo,
    const float* __restrict__ bf_, const float* __restrict__ bo,
    const float* __restrict__ A_param,
    float* __restrict__ A_t, float* __restrict__ beff, u16* __restrict__ Mrow) {
  const int wg = blockIdx.x, t = threadIdx.x;
  if (wg < 128) {
    const int idx = wg * 256 + t;          // 0..32767
    const int cout = idx >> 9;             // 0..63
    const int k = idx & 511;               // 0..511 = dir*128 + d
    float s = 0.f;
    for (int d = 0; d < 128; ++d) s = fmaf(Wo[cout * 128 + d], Wf[d * 512 + k], s);
    const int dir = k >> 7, dm = k & 127;
    Mrow[(dir * 64 + cout) * 128 + dm] = f2bf(s);
  } else {
    if (t < 128) A_t[t] = tanhf(A_param[t]);
    if (t < 64) {
      float s = bo[t];
      for (int d = 0; d < 128; ++d) s = fmaf(Wo[t * 128 + d], bf_[d], s);
      beff[t] = s;
    }
  }
}

extern __shared__ char smem[];

// Load combine A-fragments (M rows) for 2 dirs straight into registers.
DEVINL void load_mfrags(const u16* __restrict__ Mrow, int dir_base, int lane,
                        bf16x8 (&afr)[2][4][4]) {
  const int l15 = lane & 15, kg = lane >> 4;
#pragma unroll
  for (int dir = 0; dir < 2; ++dir)
#pragma unroll
    for (int ct = 0; ct < 4; ++ct)
#pragma unroll
      for (int ks = 0; ks < 4; ++ks)
        afr[dir][ct][ks] = *(const bf16x8*)(
            Mrow + ((size_t)(dir_base + dir) * 64 + ct * 16 + l15) * 128 + ks * 32 + kg * 8);
}

// Pipelined in-place scan along pos for one d-column. REV: descending pos.
template <bool REV>
DEVINL void scan_col(u16* buf, int d, float A, float Bv) {
  float hv = 0.f;
  float nx[8];
#pragma unroll
  for (int j = 0; j < 8; ++j) {
    const int idx = REV ? (127 - j) : j;
    nx[j] = bf2f(buf[idx * XTS + d]);
  }
  for (int ib = 0; ib < 128; ib += 8) {
    float cur[8];
#pragma unroll
    for (int j = 0; j < 8; ++j) cur[j] = nx[j];
    if (ib + 8 < 128) {
#pragma unroll
      for (int j = 0; j < 8; ++j) {
        const int idx = REV ? (127 - (ib + 8 + j)) : (ib + 8 + j);
        nx[j] = bf2f(buf[idx * XTS + d]);
      }
    }
#pragma unroll
    for (int j = 0; j < 8; ++j) {
      const int idx = REV ? (127 - (ib + j)) : (ib + j);
      hv = fmaf(A, hv, Bv * cur[j]);
      buf[idx * XTS + d] = f2bf(hv);
    }
  }
}

// Combine: S[64c x 128pos] = sum over 2 dirs of M[dir] @ h[dir] (MFMA, A-frags in regs).
DEVINL void combine_mfma(const u16* H0, const u16* H1, const bf16x8 (&afr)[2][4][4],
                         int t, float* OutS) {
  const int lane = t & 63, wv = t >> 6;
  const int l15 = lane & 15;
  const int kgrp = (lane >> 4) * 16;
  f32x4v acc[4][2];
#pragma unroll
  for (int i = 0; i < 4; ++i)
#pragma unroll
    for (int j = 0; j < 2; ++j) acc[i][j] = (f32x4v)0.f;

#pragma unroll
  for (int dir = 0; dir < 2; ++dir) {
    const u16* Hsrc = dir ? H1 : H0;
#pragma unroll
    for (int ks = 0; ks < 4; ++ks) {
      bf16x8 bfr[2];
#pragma unroll
      for (int pt = 0; pt < 2; ++pt)
        bfr[pt] = *(const bf16x8*)((const char*)Hsrc +
                    (wv * 32 + pt * 16 + l15) * (XTS * 2) + ks * 64 + kgrp);
#pragma unroll
      for (int ct = 0; ct < 4; ++ct)
#pragma unroll
        for (int pt = 0; pt < 2; ++pt)
          acc[ct][pt] = __builtin_amdgcn_mfma_f32_16x16x32_bf16(afr[dir][ct][ks], bfr[pt], acc[ct][pt], 0, 0, 0);
    }
  }
  __syncthreads();   // all H reads done before OutS overwrites the Xt region
#pragma unroll
  for (int ct = 0; ct < 4; ++ct)
#pragma unroll
    for (int pt = 0; pt < 2; ++pt)
#pragma unroll
      for (int r = 0; r < 4; ++r)
        OutS[(ct * 16 + (lane >> 4) * 4 + r) * 134 + wv * 32 + pt * 16 + l15] = acc[ct][pt][r];
  __syncthreads();
}

// ---------------- P1: x = Wi@F_mod + bi (MFMA), scans lr/rl, MFMA combine ----------------
__global__ __launch_bounds__(256, 2) void k_horiz(
    const float* __restrict__ F_in, const float* __restrict__ prior,
    const float* __restrict__ Wi, const float* __restrict__ bi,
    const float* __restrict__ Bp, const float* __restrict__ alpha_p,
    const float* __restrict__ A_t, const u16* __restrict__ Mrow,
    u16* __restrict__ x_out, float* __restrict__ out_partial) {
  u16* Xt = (u16*)smem;                     // [128 pos][XTS]: x, then h_rl (in place)
  u16* Hl = (u16*)(smem + XT_BYTES);        // F^T staging, then copy of x -> h_lr
  char* FT = (char*)Hl;                     // [128 w][128B] bf16 FmodT, XOR-swizzled
  float* OutS = (float*)smem;               // epilogue union with Xt

  const int t = threadIdx.x;
  const int lane = t & 63, wv = t >> 6, l15 = lane & 15, kg = lane >> 4;
  const int bid = blockIdx.x, b = bid >> 7, h = bid & 127;

  // ---- Wi B-frags (k=c, n=d) into regs: bWi[nt][ks] ----
  bf16x8 bWi[8][2];
#pragma unroll
  for (int nt = 0; nt < 8; ++nt)
#pragma unroll
    for (int ks = 0; ks < 2; ++ks) {
      const float* wp = Wi + (nt * 16 + l15) * 64 + ks * 32 + kg * 8;
      const f32x4 a = *(const f32x4*)(wp);
      const f32x4 c = *(const f32x4*)(wp + 4);
      union { bf16x8 v; uint4 u; } cv;
      cv.u.x = pack2(a.x, a.y);  cv.u.y = pack2(a.z, a.w);
      cv.u.z = pack2(c.x, c.y);  cv.u.w = pack2(c.z, c.w);
      bWi[nt][ks] = cv.v;
    }

  // ---- stage Fmod^T (bf16) into FT: row w = 64 c (128B), swz byte^((w&7)<<4) ----
  {
    const int w = t & 127, ch = t >> 7;
    const float alpha = alpha_p[0];
    const float pv = prior[(b * 128 + h) * 128 + w];
    const float* Fb = F_in + ((size_t)b * 64 + ch * 32) * 16384 + h * 128 + w;
    const u32 sw = (u32)((w & 7) << 4);
    char* rowp = FT + w * 128;
#pragma unroll
    for (int q = 0; q < 4; ++q) {
      float fv[8];
#pragma unroll
      for (int j = 0; j < 8; ++j) fv[j] = fmaf(alpha, pv, Fb[(q * 8 + j) * 16384]);
      uint4 pk;
      pk.x = pack2(fv[0], fv[1]); pk.y = pack2(fv[2], fv[3]);
      pk.z = pack2(fv[4], fv[5]); pk.w = pack2(fv[6], fv[7]);
      *(uint4*)(rowp + ((ch * 64 + q * 16) ^ sw)) = pk;
    }
  }
  __syncthreads();

  // ---- x-compute MFMA: D[w][d]; wave covers w in [wv*32, wv*32+32) ----
  {
    float biv[8];
#pragma unroll
    for (int nt = 0; nt < 8; ++nt) biv[nt] = bi[nt * 16 + l15];

    f32x4v acc[2][8];
#pragma unroll
    for (int i = 0; i < 2; ++i)
#pragma unroll
      for (int j = 0; j < 8; ++j) acc[i][j] = (f32x4v)0.f;

#pragma unroll
    for (int ks = 0; ks < 2; ++ks)
#pragma unroll
      for (int mt = 0; mt < 2; ++mt) {
        const int row = wv * 32 + mt * 16 + l15;
        const bf16x8 aF = *(const bf16x8*)(FT + row * 128 + ((ks * 64 + kg * 16) ^ ((row & 7) << 4)));
#pragma unroll
        for (int nt = 0; nt < 8; ++nt)
          acc[mt][nt] = __builtin_amdgcn_mfma_f32_16x16x32_bf16(aF, bWi[nt][ks], acc[mt][nt], 0, 0, 0);
      }

    // store D (+bias) -> Xt[w][d] bf16
#pragma unroll
    for (int mt = 0; mt < 2; ++mt)
#pragma unroll
      for (int nt = 0; nt < 8; ++nt)
#pragma unroll
        for (int r = 0; r < 4; ++r) {
          const int w = wv * 32 + mt * 16 + kg * 4 + r;
          Xt[w * XTS + nt * 16 + l15] = f2bf(acc[mt][nt][r] + biv[nt]);
        }
  }
  __syncthreads();

  // ---- x_out global write + Xt -> Hl copy (overwrites FT) ----
  {
    u16* xg = x_out + (size_t)(b * 128 + h) * 16384;   // [w][d] plane
    for (int i = t; i < 2048; i += 256) {
      const int r = i >> 4, q = i & 15;
      *(uint4*)(xg + r * 128 + q * 8) = *(const uint4*)((const char*)Xt + r * (XTS * 2) + q * 16);
    }
    for (int i = t; i < XT_BYTES / 16; i += 256)
      *(uint4*)((char*)Hl + i * 16) = *(const uint4*)((const char*)Xt + i * 16);
  }

  // combine A-frags -> regs (latency overlaps copy/scans)
  bf16x8 afr[2][4][4];
  load_mfrags(Mrow, 0, lane, afr);
  __syncthreads();

  // ---- scans in place: lr in Hl, rl in Xt ----
  {
    const int d = t & 127;
    const float A = A_t[d], Bv = Bp[d];
    if (t < 128) scan_col<false>(Hl, d, A, Bv);
    else         scan_col<true>(Xt, d, A, Bv);
  }
  __syncthreads();

  combine_mfma(Hl, Xt, afr, t, OutS);

  // ---- OutS -> out_partial[b][c][h][w] (raw, pre-gamma) ----
  float* og = out_partial + ((size_t)b * 64 * 128 + h) * 128;
  for (int i = t; i < 8192; i += 256) {
    const int c = i >> 7, ww = i & 127;
    og[c * 16384 + ww] = OutS[c * 134 + ww];
  }
}

// ---------------- P2: vertical scans tb/bt + MFMA combine -> accT[b,c,w,h] ----------------
__global__ __launch_bounds__(256, 2) void k_vert(
    const u16* __restrict__ x_ws, const float* __restrict__ Bp,
    const float* __restrict__ A_t, const u16* __restrict__ Mrow,
    u16* __restrict__ accT) {
  u16* Xv = (u16*)smem;                     // [128 h][XTS]: x, then h_bt
  u16* Hv = (u16*)(smem + XT_BYTES);        // copy, then h_tb
  float* OutS = (float*)smem;

  const int t = threadIdx.x;
  const int lane = t & 63;
  const int bid = blockIdx.x, b = bid >> 7, w = bid & 127;

  // load x[b][:][w][:] -> Xv[h][d]
  for (int i = t; i < 2048; i += 256) {
    const int hh = i >> 4, q = i & 15;
    const uint4 v = *(const uint4*)(x_ws + ((size_t)(b * 128 + hh) * 128 + w) * 128 + q * 8);
    *(uint4*)((char*)Xv + hh * (XTS * 2) + q * 16) = v;
  }
  bf16x8 afr[2][4][4];
  load_mfrags(Mrow, 2, lane, afr);
  __syncthreads();
  for (int i = t; i < XT_BYTES / 16; i += 256)
    *(uint4*)((char*)Hv + i * 16) = *(const uint4*)((const char*)Xv + i * 16);
  __syncthreads();

  // scans: tb in Hv (ascending h), bt in Xv (descending)
  {
    const int d = t & 127;
    const float A = A_t[d], Bv = Bp[d];
    if (t < 128) scan_col<false>(Hv, d, A, Bv);
    else         scan_col<true>(Xv, d, A, Bv);
  }
  __syncthreads();

  combine_mfma(Hv, Xv, afr, t, OutS);

  // ---- OutS (S_v[c][h] at fixed w) -> accT[b][c][w][h] bf16 ----
  for (int i = t; i < 4096; i += 256) {
    const int c = i >> 6, h2 = (i & 63) * 2;
    const u32 pk = pack2(OutS[c * 134 + h2], OutS[c * 134 + h2 + 1]);
    *(u32*)(accT + ((size_t)(b * 64 + c) * 128 + w) * 128 + h2) = pk;
  }
}

// ---------------- F: out = F_mod + gamma*(S_h + S_v^T + beff) ----------------
__global__ __launch_bounds__(256) void k_final(
    const float* __restrict__ F_in, const float* __restrict__ prior,
    const float* __restrict__ alpha_p, const float* __restrict__ gamma_p,
    const float* __restrict__ beff, const u16* __restrict__ accT,
    float* __restrict__ out) {
  u16* Xu = (u16*)smem;
  u32* Xw = (u32*)smem;
  const int t = threadIdx.x;
  const int bid = blockIdx.x, b = bid >> 6, c = bid & 63;
  const size_t base = (size_t)bid * 16384;   // (b,c) plane

  for (int i = t; i < 2048; i += 256) {
    const int r = i >> 4, j = i & 15;   // r = w row of accT plane
    const uint4 v = *(const uint4*)(accT + base + r * 128 + j * 8);
    u32* dst = Xw + r * 66 + j * 4;
    dst[0] = v.x; dst[1] = v.y; dst[2] = v.z; dst[3] = v.w;
  }
  __syncthreads();
  const float alpha = alpha_p[0], gamma = gamma_p[0];
  const float be = beff[c];
  for (int i = t; i < 2048; i += 256) {
    const int hh = i >> 4, w8 = (i & 15) * 8;
    float sv[8];
#pragma unroll
    for (int q = 0; q < 8; ++q) sv[q] = bf2f(Xu[(w8 + q) * XS + hh]);
    const size_t off = base + hh * 128 + w8;
    const float* Fp = F_in + off;
    float* Op = out + off;
    const float* Pp = prior + (b * 128 + hh) * 128 + w8;
#pragma unroll
    for (int q = 0; q < 8; ++q) {
      Op[q] = Fp[q] + alpha * Pp[q] + gamma * (Op[q] + be + sv[q]);
    }
  }
}

extern "C" void kernel_launch(void* const* d_in, const int* in_sizes, int n_in,
                              void* d_out, int out_size, void* d_ws, size_t ws_size,
                              hipStream_t stream) {
  const float* F_in   = (const float*)d_in[0];
  const float* prior  = (const float*)d_in[1];
  const float* Wi     = (const float*)d_in[2];
  const float* bi     = (const float*)d_in[3];
  const float* A_par  = (const float*)d_in[4];
  const float* B_par  = (const float*)d_in[5];
  const float* alpha  = (const float*)d_in[6];
  const float* gamma  = (const float*)d_in[7];
  const float* Wf     = (const float*)d_in[8];
  const float* bf_    = (const float*)d_in[9];
  const float* Wo     = (const float*)d_in[10];
  const float* bo     = (const float*)d_in[11];
  float* out = (float*)d_out;

  char* ws = (char*)d_ws;
  float* A_t   = (float*)ws;                       // 512 B
  float* beff  = (float*)(ws + 512);               // 256 B
  u16*   Mrow  = (u16*)(ws + 1024);                // 64 KB: [4][64][128] bf16
  u16*   x_ws  = (u16*)(ws + 66560);               // 33.5 MB: x[b][h][w][d] bf16
  u16*   accT  = (u16*)(ws + 66560 + 33554432);    // 16.8 MB: [b][c][w][h] bf16

  hipFuncSetAttribute((const void*)k_horiz, hipFuncAttributeMaxDynamicSharedMemorySize, LDS_MAIN);
  hipFuncSetAttribute((const void*)k_vert,  hipFuncAttributeMaxDynamicSharedMemorySize, LDS_MAIN);

  k_pre  <<<129, 256, 0, stream>>>(Wf, Wo, bf_, bo, A_par, A_t, beff, Mrow);
  k_horiz<<<1024, 256, LDS_MAIN, stream>>>(F_in, prior, Wi, bi, B_par, alpha, A_t, Mrow, x_ws, out);
  k_vert <<<1024, 256, LDS_MAIN, stream>>>(x_ws, B_par, A_t, Mrow, accT);
  k_final<<<512, 256, LDS_X, stream>>>(F_in, prior, alpha, gamma, beff, accT, out);
}